// Round 1
// baseline (527.504 us; speedup 1.0000x reference)
//
#include <hip/hip_runtime.h>
#include <float.h>

#define NUM_CODES 1024
#define DIM 64

// Prep: transpose embeddings [64][1024] -> Et [1024][64], and per-code norms.
__global__ void vq_prep(const float* __restrict__ E,
                        float* __restrict__ Et,
                        float* __restrict__ nrm) {
    int k = blockIdx.x;      // code index 0..1023
    int d = threadIdx.x;     // dim index 0..63
    float v = E[d * NUM_CODES + k];
    Et[k * DIM + d] = v;
    float s = v * v;
    #pragma unroll
    for (int off = 32; off; off >>= 1) s += __shfl_down(s, off, 64);
    if (d == 0) nrm[k] = s;
}

// Main: one thread per row. Row in registers; stream codes via uniform
// (scalar) loads from the transposed table; 8 independent FMA chains.
__global__ __launch_bounds__(256) void vq_main(const float* __restrict__ x,
                                               const float* __restrict__ Et,
                                               const float* __restrict__ nrm,
                                               float* __restrict__ out,
                                               int nrows) {
    int row = blockIdx.x * 256 + threadIdx.x;
    if (row >= nrows) return;

    float z[DIM];
    const float4* xr = reinterpret_cast<const float4*>(x + (size_t)row * DIM);
    #pragma unroll
    for (int i = 0; i < DIM / 4; ++i) {
        float4 v = xr[i];
        z[4*i+0] = v.x; z[4*i+1] = v.y; z[4*i+2] = v.z; z[4*i+3] = v.w;
    }
    float zn = 0.f;
    #pragma unroll
    for (int d = 0; d < DIM; ++d) zn += z[d] * z[d];

    float best = FLT_MAX;
    int bidx = 0;
    for (int k0 = 0; k0 < NUM_CODES; k0 += 8) {
        float acc[8];
        #pragma unroll
        for (int j = 0; j < 8; ++j) acc[j] = 0.f;
        #pragma unroll
        for (int d = 0; d < DIM; ++d) {
            #pragma unroll
            for (int j = 0; j < 8; ++j) {
                acc[j] = __builtin_fmaf(z[d], Et[(k0 + j) * DIM + d], acc[j]);
            }
        }
        #pragma unroll
        for (int j = 0; j < 8; ++j) {
            // match reference: (||z||^2 + ||e||^2) - 2*sim
            float dist = (zn + nrm[k0 + j]) - 2.0f * acc[j];
            if (dist < best) { best = dist; bidx = k0 + j; }  // first-min tiebreak
        }
    }

    // Gather exact embedding row (bit-exact vs reference's take())
    const float4* er = reinterpret_cast<const float4*>(Et + (size_t)bidx * DIM);
    float4* orow = reinterpret_cast<float4*>(out + (size_t)row * DIM);
    #pragma unroll
    for (int i = 0; i < DIM / 4; ++i) orow[i] = er[i];
}

extern "C" void kernel_launch(void* const* d_in, const int* in_sizes, int n_in,
                              void* d_out, int out_size, void* d_ws, size_t ws_size,
                              hipStream_t stream) {
    const float* x = (const float*)d_in[0];
    const float* E = (const float*)d_in[1];
    float* out = (float*)d_out;

    float* Et  = (float*)d_ws;                  // 1024*64 floats = 256 KiB
    float* nrm = Et + NUM_CODES * DIM;          // 1024 floats

    int nrows = in_sizes[0] / DIM;              // 65536

    vq_prep<<<NUM_CODES, DIM, 0, stream>>>(E, Et, nrm);
    vq_main<<<(nrows + 255) / 256, 256, 0, stream>>>(x, Et, nrm, out, nrows);
}

// Round 2
// 181.329 us; speedup vs baseline: 2.9091x; 2.9091x over previous
//
#include <hip/hip_runtime.h>
#include <float.h>

#define K_CODES 1024
#define DIM 64
#define BR 128   // rows per block
#define BC 128   // codes per chunk

// Prep: transpose embeddings [64][1024] -> Et [1024][64] (gather source),
// and per-code squared norms.
__global__ void vq_prep(const float* __restrict__ E,
                        float* __restrict__ Et,
                        float* __restrict__ nrm) {
    int k = blockIdx.x;      // code
    int d = threadIdx.x;     // dim
    float v = E[d * K_CODES + k];
    Et[k * DIM + d] = v;
    float s = v * v;
    #pragma unroll
    for (int off = 32; off; off >>= 1) s += __shfl_down(s, off, 64);
    if (d == 0) nrm[k] = s;
}

template<bool FIRST>
__device__ __forceinline__ void vq_chunk(const float* __restrict__ xT,
                                         const float* __restrict__ eT,
                                         int ty, int tx,
                                         float zn8[8], float acc[8][8])
{
    #pragma unroll
    for (int ri = 0; ri < 8; ++ri)
        #pragma unroll
        for (int cj = 0; cj < 8; ++cj) acc[ri][cj] = 0.f;

    const float* xp = xT + ty * 8;
    const float* ep = eT + tx * 8;
    #pragma unroll 2
    for (int d = 0; d < DIM; ++d) {
        float4 z0 = *(const float4*)(xp + d * BR);
        float4 z1 = *(const float4*)(xp + d * BR + 4);
        float4 e0 = *(const float4*)(ep + d * BC);
        float4 e1 = *(const float4*)(ep + d * BC + 4);
        float zb[8] = {z0.x, z0.y, z0.z, z0.w, z1.x, z1.y, z1.z, z1.w};
        float eb[8] = {e0.x, e0.y, e0.z, e0.w, e1.x, e1.y, e1.z, e1.w};
        if (FIRST) {
            #pragma unroll
            for (int ri = 0; ri < 8; ++ri)
                zn8[ri] = __builtin_fmaf(zb[ri], zb[ri], zn8[ri]);
        }
        #pragma unroll
        for (int ri = 0; ri < 8; ++ri)
            #pragma unroll
            for (int cj = 0; cj < 8; ++cj)
                acc[ri][cj] = __builtin_fmaf(zb[ri], eb[cj], acc[ri][cj]);
    }
}

__global__ __launch_bounds__(256, 2) void vq_main(
    const float* __restrict__ x, const float* __restrict__ E,
    const float* __restrict__ Et, const float* __restrict__ nrm,
    float* __restrict__ out, int nrows)
{
    __shared__ float smem[16384 + 128];
    float*  xT      = smem;                     // [64][BR]  32 KB (reused as red)
    float*  eT      = smem + 8192;              // [64][BC]  32 KB
    float2* red     = (float2*)smem;            // [128][17] pairs, after xT done
    int*    bidxArr = (int*)(smem + 16384);     // 128 ints

    const int t  = threadIdx.x;
    const int tx = t & 15;
    const int ty = t >> 4;
    const int r0 = blockIdx.x * BR;
    if (r0 >= nrows) return;

    // ---- stage x-tile transposed: xT[d][r] ----
    #pragma unroll
    for (int i = 0; i < 8; ++i) {
        int idx = i * 256 + t;
        int r  = idx >> 4;
        int c4 = (idx & 15) << 2;
        float4 v = *(const float4*)(x + (size_t)(r0 + r) * DIM + c4);
        xT[(c4 + 0) * BR + r] = v.x;
        xT[(c4 + 1) * BR + r] = v.y;
        xT[(c4 + 2) * BR + r] = v.z;
        xT[(c4 + 3) * BR + r] = v.w;
    }

    float best[8];
    int   bestc[8];
    float zn8[8];
    #pragma unroll
    for (int ri = 0; ri < 8; ++ri) { best[ri] = FLT_MAX; bestc[ri] = 0; zn8[ri] = 0.f; }

    float acc[8][8];

    #pragma unroll 1
    for (int chunk = 0; chunk < K_CODES / BC; ++chunk) {
        const int c0 = chunk * BC;
        __syncthreads();
        // stage eT[d][c] from E's native [d][code] layout
        #pragma unroll
        for (int i = 0; i < 8; ++i) {
            int idx = i * 256 + t;
            int d  = idx >> 5;
            int c4 = (idx & 31) << 2;
            *(float4*)(eT + d * BC + c4) =
                *(const float4*)(E + d * K_CODES + c0 + c4);
        }
        __syncthreads();

        if (chunk == 0) vq_chunk<true >(xT, eT, ty, tx, zn8, acc);
        else            vq_chunk<false>(xT, eT, ty, tx, zn8, acc);

        // distances + running argmin (matches ref: (zn + ne) - 2*sim, fma rounds once)
        float4 n0 = *(const float4*)(nrm + c0 + tx * 8);
        float4 n1 = *(const float4*)(nrm + c0 + tx * 8 + 4);
        float nb[8] = {n0.x, n0.y, n0.z, n0.w, n1.x, n1.y, n1.z, n1.w};
        #pragma unroll
        for (int cj = 0; cj < 8; ++cj) {
            int code = c0 + tx * 8 + cj;
            #pragma unroll
            for (int ri = 0; ri < 8; ++ri) {
                float dist = __builtin_fmaf(-2.f, acc[ri][cj], zn8[ri] + nb[cj]);
                if (dist < best[ri]) { best[ri] = dist; bestc[ri] = code; }
            }
        }
    }

    // ---- per-row reduce across the 16 tx-threads ----
    __syncthreads();   // done reading xT; safe to reuse as red
    #pragma unroll
    for (int ri = 0; ri < 8; ++ri)
        red[(ty * 8 + ri) * 17 + tx] = make_float2(best[ri], __int_as_float(bestc[ri]));
    __syncthreads();

    if (t < BR) {
        float bv = FLT_MAX; int bi = 0x7fffffff;
        #pragma unroll
        for (int i = 0; i < 16; ++i) {
            float2 p = red[t * 17 + i];
            int ci = __float_as_int(p.y);
            if (p.x < bv || (p.x == bv && ci < bi)) { bv = p.x; bi = ci; }
        }
        bidxArr[t] = bi;
    }
    __syncthreads();

    // ---- gather exact embedding rows (bit-exact output) ----
    {
        int rl = t >> 1, half = t & 1;
        int code = bidxArr[rl];
        const float4* src = (const float4*)(Et + (size_t)code * DIM + half * 32);
        float4* dst = (float4*)(out + (size_t)(r0 + rl) * DIM + half * 32);
        #pragma unroll
        for (int j = 0; j < 8; ++j) dst[j] = src[j];
    }
}

extern "C" void kernel_launch(void* const* d_in, const int* in_sizes, int n_in,
                              void* d_out, int out_size, void* d_ws, size_t ws_size,
                              hipStream_t stream) {
    const float* x = (const float*)d_in[0];
    const float* E = (const float*)d_in[1];
    float* out = (float*)d_out;

    float* Et  = (float*)d_ws;                  // 1024*64 floats
    float* nrm = Et + K_CODES * DIM;            // 1024 floats

    int nrows = in_sizes[0] / DIM;              // 65536

    vq_prep<<<K_CODES, DIM, 0, stream>>>(E, Et, nrm);
    vq_main<<<(nrows + BR - 1) / BR, 256, 0, stream>>>(x, E, Et, nrm, out, nrows);
}

// Round 4
// 180.223 us; speedup vs baseline: 2.9270x; 1.0061x over previous
//
#include <hip/hip_runtime.h>
#include <float.h>

#define K_CODES 1024
#define DIM 64
#define BR 128
#define SAFE_MARGIN 1.0e-3f

typedef __attribute__((ext_vector_type(8))) short bf16x8;
typedef __attribute__((ext_vector_type(8))) unsigned short u16x8;
typedef __attribute__((ext_vector_type(4))) float f32x4;

__device__ __forceinline__ unsigned short f2bf(float f) {
    unsigned int u = __float_as_uint(f);
    u += 0x7fff + ((u >> 16) & 1);          // round-to-nearest-even
    return (unsigned short)(u >> 16);
}
__device__ __forceinline__ float bf2f(unsigned short h) {
    return __uint_as_float(((unsigned int)h) << 16);
}
// XOR swizzle for 128-byte LDS rows (G4 pattern): kills the 16/32-way
// same-column bank conflicts on ds_read_b128. Applied on BOTH write & read.
__device__ __forceinline__ int swz(int row, int byteInRow) {
    return row * 128 + (byteInRow ^ ((row & 7) << 4));
}

// ---------- prep: transpose E, build bf16 hi/lo splits, norms, zero counter ----------
__global__ __launch_bounds__(256) void vq_prep2(
    const float* __restrict__ E, float* __restrict__ Et,
    unsigned short* __restrict__ Eh, unsigned short* __restrict__ El,
    float* __restrict__ nrm, int* __restrict__ cnt)
{
    __shared__ float T[64 * 65];
    const int t = threadIdx.x;
    const int k0 = blockIdx.x * 64;
    if (blockIdx.x == 0 && t == 0) *cnt = 0;
    #pragma unroll
    for (int i = 0; i < 16; ++i) {
        int idx = i * 256 + t;
        int d = idx >> 6, kk = idx & 63;
        T[d * 65 + kk] = E[d * K_CODES + k0 + kk];   // coalesced 256B rows
    }
    __syncthreads();
    #pragma unroll
    for (int i = 0; i < 16; ++i) {
        int idx = i * 256 + t;
        int kk = idx >> 6, d = idx & 63;
        float v = T[d * 65 + kk];
        Et[(size_t)(k0 + kk) * DIM + d] = v;         // coalesced writes
        unsigned short h = f2bf(v);
        Eh[(size_t)(k0 + kk) * DIM + d] = h;
        El[(size_t)(k0 + kk) * DIM + d] = f2bf(v - bf2f(h));
    }
    if (t < 64) {
        float s = 0.f;
        #pragma unroll
        for (int d = 0; d < DIM; ++d) {
            float v = T[d * 65 + t];
            s = __builtin_fmaf(v, v, s);
        }
        nrm[k0 + t] = s;
    }
}

// ---------- main: bf16x3 MFMA distances + top-2 margin gate + fused gather ----------
__global__ __launch_bounds__(256, 2) void vq_mfma(
    const float* __restrict__ x,
    const unsigned short* __restrict__ Eh,
    const unsigned short* __restrict__ El,
    const float* __restrict__ nrm,
    const float* __restrict__ Et,
    float* __restrict__ out,
    int* __restrict__ cnt, int* __restrict__ list)
{
    __shared__ char lds[66048];
    char* Ah = lds;                  // 16 KB: 128 rows x 128 B (bf16 hi of z)
    char* Al = lds + 16384;          // 16 KB: lo
    char* Bh = lds + 32768;          // 16 KB: 128 codes x 128 B (bf16 hi of e, [code][k])
    char* Bl = lds + 49152;          // 16 KB: lo
    int* bidx = (int*)(lds + 65536); // 128 winning codes

    const int t    = threadIdx.x;
    const int lane = t & 63;
    const int wv   = t >> 6;
    const int col  = lane & 15;
    const int q    = lane >> 4;
    const int koff = q * 16;                  // byte offset of lane's 8-elem k-group
    const long r0  = (long)blockIdx.x * BR;

    // ---- stage A: load x rows, split fp32 -> bf16 hi/lo, swizzled LDS write ----
    {
        int row = t >> 1, h = t & 1;
        const float4* src = (const float4*)(x + (r0 + row) * DIM + h * 32);
        float v[32];
        #pragma unroll
        for (int i = 0; i < 8; ++i) {
            float4 f = src[i];
            v[4*i+0] = f.x; v[4*i+1] = f.y; v[4*i+2] = f.z; v[4*i+3] = f.w;
        }
        unsigned short hi[32], lo[32];
        #pragma unroll
        for (int i = 0; i < 32; ++i) {
            hi[i] = f2bf(v[i]);
            lo[i] = f2bf(v[i] - bf2f(hi[i]));  // exact residual, then RNE
        }
        #pragma unroll
        for (int s = 0; s < 2; ++s) {
            int seg = h * 2 + s;               // 16-elem (32 B) group
            *(u16x8*)(Ah + swz(row, seg*32))      = *(u16x8*)(hi + s*16);
            *(u16x8*)(Ah + swz(row, seg*32 + 16)) = *(u16x8*)(hi + s*16 + 8);
            *(u16x8*)(Al + swz(row, seg*32))      = *(u16x8*)(lo + s*16);
            *(u16x8*)(Al + swz(row, seg*32 + 16)) = *(u16x8*)(lo + s*16 + 8);
        }
    }
    __syncthreads();

    // ---- A fragments, held in VGPRs for the whole kernel ----
    // mfma_f32_16x16x32_bf16: A[row=lane&15][k=(lane>>4)*8+j]
    bf16x8 aH[2][2], aL[2][2];
    #pragma unroll
    for (int m = 0; m < 2; ++m) {
        int arow = wv * 32 + m * 16 + col;
        #pragma unroll
        for (int kk = 0; kk < 2; ++kk) {
            aH[m][kk] = *(bf16x8*)(Ah + swz(arow, kk*64 + koff));
            aL[m][kk] = *(bf16x8*)(Al + swz(arow, kk*64 + koff));
        }
    }

    float b1[2][4], b2[2][4];
    int   i1[2][4];
    #pragma unroll
    for (int m = 0; m < 2; ++m)
        #pragma unroll
        for (int j = 0; j < 4; ++j) { b1[m][j] = FLT_MAX; b2[m][j] = FLT_MAX; i1[m][j] = 0x7fffffff; }

    for (int c0 = 0; c0 < K_CODES; c0 += 128) {
        __syncthreads();
        // stage B chunk: 128 codes x 64 dims, hi+lo, from pre-transposed global
        #pragma unroll
        for (int i = 0; i < 4; ++i) {
            int idx = i * 256 + t;
            int cr = idx >> 3, sg = idx & 7;   // 128 rows x 8 granules of 16 B
            *(u16x8*)(Bh + swz(cr, sg*16)) = *(const u16x8*)(Eh + (size_t)(c0+cr)*DIM + sg*8);
            *(u16x8*)(Bl + swz(cr, sg*16)) = *(const u16x8*)(El + (size_t)(c0+cr)*DIM + sg*8);
        }
        __syncthreads();

        #pragma unroll
        for (int nt = 0; nt < 8; ++nt) {
            int brow = nt * 16 + col;          // B[k][col]: frag from [code][k] store
            bf16x8 bH0 = *(bf16x8*)(Bh + swz(brow, koff));
            bf16x8 bH1 = *(bf16x8*)(Bh + swz(brow, 64 + koff));
            bf16x8 bL0 = *(bf16x8*)(Bl + swz(brow, koff));
            bf16x8 bL1 = *(bf16x8*)(Bl + swz(brow, 64 + koff));
            int code = c0 + nt * 16 + col;
            float ne = nrm[code];
            #pragma unroll
            for (int m = 0; m < 2; ++m) {
                f32x4 acc = {0.f, 0.f, 0.f, 0.f};
                acc = __builtin_amdgcn_mfma_f32_16x16x32_bf16(aH[m][0], bH0, acc, 0,0,0);
                acc = __builtin_amdgcn_mfma_f32_16x16x32_bf16(aH[m][1], bH1, acc, 0,0,0);
                acc = __builtin_amdgcn_mfma_f32_16x16x32_bf16(aH[m][0], bL0, acc, 0,0,0);
                acc = __builtin_amdgcn_mfma_f32_16x16x32_bf16(aH[m][1], bL1, acc, 0,0,0);
                acc = __builtin_amdgcn_mfma_f32_16x16x32_bf16(aL[m][0], bH0, acc, 0,0,0);
                acc = __builtin_amdgcn_mfma_f32_16x16x32_bf16(aL[m][1], bH1, acc, 0,0,0);
                // dist sans zn (constant per row: ranking & margins unaffected)
                #pragma unroll
                for (int j = 0; j < 4; ++j) {
                    float dist = __builtin_fmaf(-2.f, acc[j], ne);
                    if (dist < b1[m][j]) { b2[m][j] = b1[m][j]; b1[m][j] = dist; i1[m][j] = code; }
                    else if (dist < b2[m][j]) { b2[m][j] = dist; }
                }
            }
        }
    }

    // ---- top-2 merge across the 16 lanes (cols) holding each row ----
    #pragma unroll
    for (int msk = 1; msk < 16; msk <<= 1) {
        #pragma unroll
        for (int m = 0; m < 2; ++m)
            #pragma unroll
            for (int j = 0; j < 4; ++j) {
                float o1 = __shfl_xor(b1[m][j], msk, 64);
                int   oi = __shfl_xor(i1[m][j], msk, 64);
                float o2 = __shfl_xor(b2[m][j], msk, 64);
                bool take = (o1 < b1[m][j]) || (o1 == b1[m][j] && oi < i1[m][j]);
                float worst = take ? b1[m][j] : o1;
                if (take) { b1[m][j] = o1; i1[m][j] = oi; }
                b2[m][j] = fminf(fminf(b2[m][j], o2), worst);
            }
    }
    if (col == 0) {
        #pragma unroll
        for (int m = 0; m < 2; ++m)
            #pragma unroll
            for (int j = 0; j < 4; ++j) {
                int rowl = wv * 32 + m * 16 + q * 4 + j;   // C/D: row=(lane>>4)*4+reg
                bidx[rowl] = i1[m][j];
                if (b2[m][j] - b1[m][j] <= SAFE_MARGIN) {  // ambiguous -> exact refine
                    int p = atomicAdd(cnt, 1);
                    list[p] = (int)(r0 + rowl);
                }
            }
    }
    __syncthreads();

    // ---- fused gather: bit-exact embedding rows ----
    {
        int rowl = t >> 1, h = t & 1;
        int code = bidx[rowl];
        const float4* src = (const float4*)(Et + (size_t)code * DIM + h * 32);
        float4* dst = (float4*)(out + (size_t)(r0 + rowl) * DIM + h * 32);
        #pragma unroll
        for (int i = 0; i < 8; ++i) dst[i] = src[i];
    }
}

// ---------- refine: exact fp32 re-solve for margin-gated rows (proven arithmetic) ----------
__global__ __launch_bounds__(256) void vq_refine(
    const float* __restrict__ x, const float* __restrict__ Et,
    const float* __restrict__ nrm, float* __restrict__ out,
    const int* __restrict__ cnt, const int* __restrict__ list)
{
    __shared__ float zsh[4][DIM];
    const int n = *cnt;
    const int wv = threadIdx.x >> 6, lane = threadIdx.x & 63;
    for (int i = blockIdx.x * 4 + wv; i < n; i += gridDim.x * 4) {
        int row = list[i];
        zsh[wv][lane] = x[(size_t)row * DIM + lane];
        float zn = 0.f;
        #pragma unroll
        for (int d = 0; d < DIM; ++d) {
            float z = zsh[wv][d];
            zn = __builtin_fmaf(z, z, zn);
        }
        float b1 = FLT_MAX; int i1v = 0x7fffffff;
        for (int cc = 0; cc < 16; ++cc) {
            int code = cc * 64 + lane;         // ascending per lane: first-min kept
            const float* ep = Et + (size_t)code * DIM;
            float acc = 0.f;
            #pragma unroll
            for (int d = 0; d < DIM; ++d)
                acc = __builtin_fmaf(zsh[wv][d], ep[d], acc);
            float dist = __builtin_fmaf(-2.f, acc, zn + nrm[code]);
            if (dist < b1) { b1 = dist; i1v = code; }
        }
        #pragma unroll
        for (int m = 1; m < 64; m <<= 1) {     // wave argmin, index tie-break
            float o1 = __shfl_xor(b1, m, 64);
            int   oi = __shfl_xor(i1v, m, 64);
            if (o1 < b1 || (o1 == b1 && oi < i1v)) { b1 = o1; i1v = oi; }
        }
        out[(size_t)row * DIM + lane] = Et[(size_t)i1v * DIM + lane];
    }
}

extern "C" void kernel_launch(void* const* d_in, const int* in_sizes, int n_in,
                              void* d_out, int out_size, void* d_ws, size_t ws_size,
                              hipStream_t stream) {
    const float* x = (const float*)d_in[0];
    const float* E = (const float*)d_in[1];
    float* out = (float*)d_out;

    char* ws = (char*)d_ws;
    float*          Et   = (float*)ws;                        // 256 KiB
    unsigned short* Eh   = (unsigned short*)(ws + 262144);    // 128 KiB
    unsigned short* El   = (unsigned short*)(ws + 393216);    // 128 KiB
    float*          nrm  = (float*)(ws + 524288);             // 4 KiB
    int*            cnt  = (int*)(ws + 528384);               // 4 B (+pad)
    int*            list = (int*)(ws + 528640);               // 256 KiB

    int nrows = in_sizes[0] / DIM;                            // 65536

    vq_prep2<<<16, 256, 0, stream>>>(E, Et, Eh, El, nrm, cnt);
    vq_mfma<<<nrows / BR, 256, 0, stream>>>(x, Eh, El, nrm, Et, out, cnt, list);
    vq_refine<<<64, 256, 0, stream>>>(x, Et, nrm, out, cnt, list);
}